// Round 7
// baseline (612.467 us; speedup 1.0000x reference)
//
#include <hip/hip_runtime.h>
#include <cfloat>

#define NTOK 65536
#define DIM  512
#define KCB  1024
#define TAU  0.25f
#define REF_CAP 4096

typedef unsigned short u16;
typedef __attribute__((ext_vector_type(8))) _Float16 half8;
typedef __attribute__((ext_vector_type(4))) float f32x4;

// ---------------- ws layout (bytes) ----------------
// 0       : idx       int[NTOK]        262144
// 262144  : esq       f32[KCB]         4096    -> 266240
// 266240  : refCount  int (16B pad)            -> 266256
// 266256  : refList   int[REF_CAP]     16384   -> 282640
// 282640  : n         f32                      -> 282656 (pad)
// 282656  : counts    int[KCB]         4096    -> 286752
// 286752  : cursor    int[KCB]         4096    -> 290848
// 290848  : base      int[KCB]         4096    -> 294944
// 294976  : E_hf      f16[KCB*DIM]     1048576 -> 1343552
// esum f32[KCB*DIM] (2 MB) aliases E_hf.. (dead after score), end 2392128
// toklist int[NTOK] lives in d_out's out2 region (dead until out24_kernel)

__device__ __forceinline__ u16 h2u(_Float16 h) {
    u16 u; __builtin_memcpy(&u, &h, 2); return u;
}

__global__ __launch_bounds__(256) void esq_kernel(const float* __restrict__ E,
                                                  float* __restrict__ esq)
{
    const int lane = threadIdx.x & 63;
    const int wv   = threadIdx.x >> 6;
    const int k    = blockIdx.x * 4 + wv;
    const float* er = E + (size_t)k * DIM + lane * 8;
    float4 a = *(const float4*)er;
    float4 b = *(const float4*)(er + 4);
    float s = a.x*a.x + a.y*a.y + a.z*a.z + a.w*a.w
            + b.x*b.x + b.y*b.y + b.z*b.z + b.w*b.w;
    for (int off = 32; off > 0; off >>= 1) s += __shfl_down(s, off, 64);
    if (lane == 0) esq[k] = s;
}

// E -> f16 (RNE), row-major [KCB][DIM]
__global__ __launch_bounds__(256) void ehalf_kernel(const float* __restrict__ E,
                                                    u16* __restrict__ Ehf)
{
    const size_t i = (size_t)blockIdx.x * 256 + threadIdx.x;   // pair index
    const float2 v = *(const float2*)(E + i * 2);
    const _Float16 h0 = (_Float16)v.x, h1 = (_Float16)v.y;
    ((unsigned int*)Ehf)[i] = ((unsigned int)h2u(h1) << 16) | h2u(h0);
}

// MFMA split-f16 scoring: 64 tokens/block (16/wave, K=512 in regs),
// 64 chunks of 16 codes; only the f16-hi E tile is staged (2-term Markidis:
// z.e ~= zh.eh + zl.eh, dropped z.el has max err ~0.07 << TAU).
__global__ __launch_bounds__(256, 3) void score_kernel(
    const float* __restrict__ z,
    const u16* __restrict__ Ehf,
    const float* __restrict__ esq,
    int* __restrict__ idx_ws, float* __restrict__ idx_out,
    int* __restrict__ refCount, int* __restrict__ refList)
{
    __shared__ _Float16 ehi_t[16 * 512];   // 16 KB, granule-swizzled rows
    __shared__ float esq_lds[KCB];         // 4 KB

    const int tid  = threadIdx.x;
    const int lane = tid & 63;
    const int wv   = tid >> 6;
    const int blk  = blockIdx.x;
    const int tokbase = blk * 64 + wv * 16;

    for (int i = tid; i < KCB; i += 256) esq_lds[i] = esq[i];

    // A fragments: 16 tokens x K=512, f16 hi/lo, in registers
    // A[row][k]: row = lane&15, k = kc*32 + (lane>>4)*8 + j
    half8 zh[16], zl[16];
    {
        const float* zr = z + (size_t)(tokbase + (lane & 15)) * DIM + ((lane >> 4) << 3);
        #pragma unroll
        for (int kc = 0; kc < 16; ++kc) {
            float4 a = *(const float4*)(zr + kc * 32);
            float4 b = *(const float4*)(zr + kc * 32 + 4);
            float v[8] = {a.x, a.y, a.z, a.w, b.x, b.y, b.z, b.w};
            half8 h, l;
            #pragma unroll
            for (int j = 0; j < 8; ++j) {
                const _Float16 hv = (_Float16)v[j];
                h[j] = hv;
                l[j] = (_Float16)(v[j] - (float)hv);
            }
            zh[kc] = h; zl[kc] = l;
        }
    }

    float d1[4], d2[4]; int i1[4];
    #pragma unroll
    for (int r = 0; r < 4; ++r) { d1[r] = FLT_MAX; d2[r] = FLT_MAX; i1[r] = KCB; }

    for (int ch = 0; ch < 64; ++ch) {
        __syncthreads();   // previous chunk's reads done before overwrite
        // stage 16-code tile (f16 rows, 1024 B each). LDS granule = lane;
        // source granule = lane ^ (r&15) so read granule g comes from
        // LDS slot g ^ (row&15): 16 distinct granules per quarter-wave ->
        // each bank-quad exactly 2x = conflict-free.
        #pragma unroll
        for (int i = 0; i < 4; ++i) {
            const int c = (wv << 2) + i;
            const size_t grow = (size_t)((ch << 4) + c) * 512;
            const int soff = (lane ^ (c & 15)) << 3;   // f16 units (16B granules)
            __builtin_amdgcn_global_load_lds(
                (const __attribute__((address_space(1))) void*)(Ehf + grow + soff),
                (__attribute__((address_space(3))) void*)&ehi_t[c * 512], 16, 0, 0);
        }
        __syncthreads();   // drains vmcnt: tile ready

        f32x4 acc = {0.f, 0.f, 0.f, 0.f};
        #pragma unroll
        for (int kc = 0; kc < 16; ++kc) {
            // B[k][col]: col = lane&15 (code row), granule g = kc*4 + (lane>>4)
            const int g = (kc << 2) + (lane >> 4);
            const int u = g ^ (lane & 15);
            const int base = (lane & 15) * 512 + (u << 3);
            const half8 eh = *(const half8*)&ehi_t[base];
            acc = __builtin_amdgcn_mfma_f32_16x16x32_f16(zh[kc], eh, acc, 0, 0, 0);
            acc = __builtin_amdgcn_mfma_f32_16x16x32_f16(zl[kc], eh, acc, 0, 0, 0);
        }

        // C/D layout: col = lane&15 -> code, row = (lane>>4)*4 + r -> token
        const int code = (ch << 4) + (lane & 15);
        const float ej = esq_lds[code];
        #pragma unroll
        for (int r = 0; r < 4; ++r) {
            const float dist = fmaf(-2.0f, acc[r], ej);
            if (dist < d1[r]) { d2[r] = d1[r]; d1[r] = dist; i1[r] = code; }
            else              { d2[r] = fminf(d2[r], dist); }
        }
    }

    // merge top-2 across the 16 code-lanes (low 4 lane bits)
    #pragma unroll
    for (int off = 1; off < 16; off <<= 1) {
        #pragma unroll
        for (int r = 0; r < 4; ++r) {
            const float od1 = __shfl_xor(d1[r], off, 64);
            const int   oi1 = __shfl_xor(i1[r], off, 64);
            const float od2 = __shfl_xor(d2[r], off, 64);
            float loser;
            if (od1 < d1[r] || (od1 == d1[r] && oi1 < i1[r])) {
                loser = d1[r]; d1[r] = od1; i1[r] = oi1;
            } else {
                loser = od1;
            }
            d2[r] = fminf(fminf(d2[r], od2), loser);
        }
    }
    if ((lane & 15) == 0) {
        #pragma unroll
        for (int r = 0; r < 4; ++r) {
            const int token = tokbase + ((lane >> 4) << 2) + r;
            idx_ws[token]  = i1[r];
            idx_out[token] = (float)i1[r];
            if (d2[r] - d1[r] < TAU) {
                int slot = atomicAdd(refCount, 1);
                if (slot < REF_CAP) refList[slot] = token;
            }
        }
    }
}

// f64 exact re-scoring of near-tie tokens against all 1024 codes
__global__ __launch_bounds__(256) void refine_kernel(
    const float* __restrict__ z, const float* __restrict__ E,
    const int* __restrict__ refCount, const int* __restrict__ refList,
    int* __restrict__ idx_ws, float* __restrict__ idx_out)
{
    __shared__ double dists[KCB];
    const int lane = threadIdx.x & 63;
    const int wv   = threadIdx.x >> 6;
    int rc = *refCount; if (rc > REF_CAP) rc = REF_CAP;
    for (int r = blockIdx.x; r < rc; r += gridDim.x) {
        const int token = refList[r];
        double zr[8];
        const float* zp = z + (size_t)token * DIM + lane * 8;
        #pragma unroll
        for (int j = 0; j < 8; ++j) zr[j] = (double)zp[j];
        for (int c = wv; c < KCB; c += 4) {
            const float* ep = E + (size_t)c * DIM + lane * 8;
            double s = 0.0;
            #pragma unroll
            for (int j = 0; j < 8; ++j) { const double df = zr[j] - (double)ep[j]; s = fma(df, df, s); }
            for (int off = 32; off > 0; off >>= 1) s += __shfl_down(s, off, 64);
            if (lane == 0) dists[c] = s;
        }
        __syncthreads();
        if (threadIdx.x < 64) {
            double best = dists[lane]; int bi = lane;
            for (int c = lane + 64; c < KCB; c += 64) {
                const double dv = dists[c];
                if (dv < best) { best = dv; bi = c; }
            }
            for (int off = 32; off > 0; off >>= 1) {
                const double ob = __shfl_down(best, off, 64);
                const int    oi = __shfl_down(bi, off, 64);
                if (ob < best || (ob == best && oi < bi)) { best = ob; bi = oi; }
            }
            if (lane == 0) { idx_ws[token] = bi; idx_out[token] = (float)bi; }
        }
        __syncthreads();
    }
}

// ---- counting sort of tokens by code ----
__global__ __launch_bounds__(256) void hist_kernel(const int* __restrict__ idx,
                                                   int* __restrict__ counts)
{
    __shared__ int h[KCB];
    const int tid = threadIdx.x;
    for (int i = tid; i < KCB; i += 256) h[i] = 0;
    __syncthreads();
    const int b0 = blockIdx.x * 1024;
    #pragma unroll
    for (int j = 0; j < 4; ++j) atomicAdd(&h[idx[b0 + j * 256 + tid]], 1);
    __syncthreads();
    for (int i = tid; i < KCB; i += 256) {
        const int v = h[i];
        if (v) atomicAdd(&counts[i], v);
    }
}

__global__ __launch_bounds__(1024) void scan_kernel(const int* __restrict__ counts,
                                                    int* __restrict__ cursor,
                                                    int* __restrict__ base)
{
    const int tid = threadIdx.x, lane = tid & 63, wv = tid >> 6;
    const int v = counts[tid];
    int s = v;
    #pragma unroll
    for (int off = 1; off < 64; off <<= 1) {
        const int nb = __shfl_up(s, off, 64);
        if (lane >= off) s += nb;
    }
    __shared__ int wsum[16], wbase[16];
    if (lane == 63) wsum[wv] = s;
    __syncthreads();
    if (tid == 0) {
        int r = 0;
        for (int w = 0; w < 16; ++w) { wbase[w] = r; r += wsum[w]; }
    }
    __syncthreads();
    const int excl = wbase[wv] + s - v;
    cursor[tid] = excl;
    base[tid]   = excl;
}

__global__ __launch_bounds__(256) void scatter_kernel(const int* __restrict__ idx,
                                                      int* __restrict__ cursor,
                                                      int* __restrict__ toklist)
{
    const int b0 = blockIdx.x * 1024;
    #pragma unroll
    for (int j = 0; j < 4; ++j) {
        const int t = b0 + j * 256 + threadIdx.x;
        const int k = idx[t];
        const int slot = atomicAdd(&cursor[k], 1);
        toklist[slot] = t;
    }
}

// Uniform-work segment sum: block b owns sorted slots [b*64, b*64+64).
__global__ __launch_bounds__(256) void seg_sum_kernel(
    const float* __restrict__ z, const float* __restrict__ E,
    const int* __restrict__ toklist, const int* __restrict__ idx,
    float* __restrict__ out0, float* __restrict__ esum)
{
    __shared__ int toks[64];
    __shared__ int ks[64];
    const int tid  = threadIdx.x;
    const int seg0 = blockIdx.x * 64;
    if (tid < 64) toks[tid] = toklist[seg0 + tid];
    __syncthreads();
    if (tid < 64) ks[tid] = idx[toks[tid]];
    __syncthreads();

    const int d = tid * 2;
    int curk = ks[0];
    float2 er  = *(const float2*)(E + (size_t)curk * DIM + d);
    float2 acc = {0.f, 0.f};
    float2 v   = *(const float2*)(z + (size_t)toks[0] * DIM + d);
    for (int i = 0; i < 64; ++i) {
        const int t = toks[i];
        float2 vn;
        if (i < 63) vn = *(const float2*)(z + (size_t)toks[i + 1] * DIM + d);
        const int k = ks[i];
        if (k != curk) {                       // block-uniform branch (~2/segment)
            atomicAdd(&esum[(size_t)curk * DIM + d],     acc.x);
            atomicAdd(&esum[(size_t)curk * DIM + d + 1], acc.y);
            acc.x = 0.f; acc.y = 0.f;
            curk = k;
            er = *(const float2*)(E + (size_t)k * DIM + d);
        }
        *(float2*)(out0 + (size_t)t * DIM + d) = er;
        acc.x += v.x; acc.y += v.y;
        v = vn;
    }
    atomicAdd(&esum[(size_t)curk * DIM + d],     acc.x);
    atomicAdd(&esum[(size_t)curk * DIM + d + 1], acc.y);
}

__global__ __launch_bounds__(1024) void cs_n_kernel(const float* __restrict__ cs,
    const int* __restrict__ counts, float* __restrict__ out3,
    float* __restrict__ n_ws)
{
    const int k = threadIdx.x;
    const float ncs = 0.99f * cs[k] + 0.01f * (float)counts[k];
    out3[k] = ncs;
    float s = ncs;
    for (int off = 32; off > 0; off >>= 1) s += __shfl_down(s, off, 64);
    __shared__ float red[16];
    const int lane = k & 63, wv = k >> 6;
    if (lane == 0) red[wv] = s;
    __syncthreads();
    if (k == 0) {
        float t = 0.f;
        for (int i = 0; i < 16; ++i) t += red[i];
        n_ws[0] = t;
    }
}

__global__ __launch_bounds__(256) void out24_kernel(const float* __restrict__ ea,
    const float* __restrict__ esum, const float* __restrict__ out3,
    const float* __restrict__ n_ws, float* __restrict__ out2,
    float* __restrict__ out4)
{
    const size_t i = (size_t)blockIdx.x * 256 + threadIdx.x;
    const int k = (int)(i >> 9);
    const float n = n_ws[0];
    const float smoothed = (out3[k] + 1e-5f) / (n + 0.01024f) * n;
    const float nea = 0.99f * ea[i] + 0.01f * esum[i];
    out4[i] = nea;
    out2[i] = nea / smoothed;
}

extern "C" void kernel_launch(void* const* d_in, const int* in_sizes, int n_in,
                              void* d_out, int out_size, void* d_ws, size_t ws_size,
                              hipStream_t stream)
{
    const float* z  = (const float*)d_in[0];
    const float* E  = (const float*)d_in[1];
    const float* cs = (const float*)d_in[2];
    const float* ea = (const float*)d_in[3];

    float* out0 = (float*)d_out;                       // quantized_st [NTOK*DIM]
    float* out1 = out0 + (size_t)NTOK * DIM;           // indices (as f32) [NTOK]
    float* out2 = out1 + NTOK;                         // new_embedding [KCB*DIM]
    float* out3 = out2 + (size_t)KCB * DIM;            // new_cluster_size [KCB]
    float* out4 = out3 + KCB;                          // new_embed_avg [KCB*DIM]

    char* ws = (char*)d_ws;
    int*   idx_ws  = (int*)ws;
    float* esq     = (float*)(ws + 262144);
    int*   refCnt  = (int*)(ws + 266240);
    int*   refList = (int*)(ws + 266256);
    float* n_ws    = (float*)(ws + 282640);
    int*   counts  = (int*)(ws + 282656);
    int*   cursor  = (int*)(ws + 286752);
    int*   base    = (int*)(ws + 290848);
    u16*   Ehf     = (u16*)(ws + 294976);
    float* esum    = (float*)(ws + 294976);            // aliases Ehf (2 MB span)
    int*   toklist = (int*)out2;                       // out2 region as scratch

    hipMemsetAsync(refCnt, 0, sizeof(int), stream);
    hipMemsetAsync(counts, 0, KCB * sizeof(int), stream);

    esq_kernel<<<KCB / 4, 256, 0, stream>>>(E, esq);
    ehalf_kernel<<<(KCB * DIM / 2) / 256, 256, 0, stream>>>(E, Ehf);
    score_kernel<<<NTOK / 64, 256, 0, stream>>>(z, Ehf, esq, idx_ws, out1, refCnt, refList);
    // Ehf dead from here; zero esum over that region (stream-ordered)
    hipMemsetAsync(esum, 0, (size_t)KCB * DIM * sizeof(float), stream);
    refine_kernel<<<1024, 256, 0, stream>>>(z, E, refCnt, refList, idx_ws, out1);
    hist_kernel<<<NTOK / 1024, 256, 0, stream>>>(idx_ws, counts);
    scan_kernel<<<1, 1024, 0, stream>>>(counts, cursor, base);
    scatter_kernel<<<NTOK / 1024, 256, 0, stream>>>(idx_ws, cursor, toklist);
    seg_sum_kernel<<<NTOK / 64, 256, 0, stream>>>(z, E, toklist, idx_ws, out0, esum);
    cs_n_kernel<<<1, 1024, 0, stream>>>(cs, counts, out3, n_ws);
    out24_kernel<<<(KCB * DIM) / 256, 256, 0, stream>>>(ea, esum, out3, n_ws, out2, out4);
}

// Round 8
// 539.136 us; speedup vs baseline: 1.1360x; 1.1360x over previous
//
#include <hip/hip_runtime.h>
#include <cfloat>

#define NTOK 65536
#define DIM  512
#define KCB  1024
#define TAU  0.12f
#define REF_CAP 4096

typedef unsigned short u16;
typedef __attribute__((ext_vector_type(8))) _Float16 half8;
typedef __attribute__((ext_vector_type(4))) float f32x4;

// ---------------- ws layout (bytes) ----------------
// 0       : idx       int[NTOK]        262144
// 262144  : esq       f32[KCB]         4096    -> 266240
// 266240  : refCount  int (16B pad)            -> 266256
// 266256  : refList   int[REF_CAP]     16384   -> 282640
// 282640  : n         f32                      -> 282656 (pad)
// 282656  : counts    int[KCB]         4096    -> 286752
// 286752  : cursor    int[KCB]         4096    -> 290848
// 290848  : base      int[KCB]         4096    -> 294944
// 294976  : E_hf      f16[KCB*DIM]     1048576 -> 1343552
// esum f32[KCB*DIM] (2 MB) aliases E_hf.. (dead after score), end 2392128
// toklist int[NTOK] lives in d_out's out2 region (dead until out24_kernel)

__device__ __forceinline__ u16 h2u(_Float16 h) {
    u16 u; __builtin_memcpy(&u, &h, 2); return u;
}

__global__ __launch_bounds__(256) void esq_kernel(const float* __restrict__ E,
                                                  float* __restrict__ esq)
{
    const int lane = threadIdx.x & 63;
    const int wv   = threadIdx.x >> 6;
    const int k    = blockIdx.x * 4 + wv;
    const float* er = E + (size_t)k * DIM + lane * 8;
    float4 a = *(const float4*)er;
    float4 b = *(const float4*)(er + 4);
    float s = a.x*a.x + a.y*a.y + a.z*a.z + a.w*a.w
            + b.x*b.x + b.y*b.y + b.z*b.z + b.w*b.w;
    for (int off = 32; off > 0; off >>= 1) s += __shfl_down(s, off, 64);
    if (lane == 0) esq[k] = s;
}

// E -> f16 (RNE), row-major [KCB][DIM]
__global__ __launch_bounds__(256) void ehalf_kernel(const float* __restrict__ E,
                                                    u16* __restrict__ Ehf)
{
    const size_t i = (size_t)blockIdx.x * 256 + threadIdx.x;   // pair index
    const float2 v = *(const float2*)(E + i * 2);
    const _Float16 h0 = (_Float16)v.x, h1 = (_Float16)v.y;
    ((unsigned int*)Ehf)[i] = ((unsigned int)h2u(h1) << 16) | h2u(h0);
}

// MFMA split-f16 scoring, 2-phase double-buffered pipeline (T3-min):
// STAGE(ch+1) issued before compute(ch); counted vmcnt(4); raw barriers.
__global__ __launch_bounds__(256, 3) void score_kernel(
    const float* __restrict__ z,
    const u16* __restrict__ Ehf,
    const float* __restrict__ esq,
    int* __restrict__ idx_ws, float* __restrict__ idx_out,
    int* __restrict__ refCount, int* __restrict__ refList)
{
    __shared__ _Float16 ehi_t[2][16 * 512];   // 2 x 16 KB, granule-swizzled rows
    __shared__ float esq_lds[KCB];            // 4 KB

    const int tid  = threadIdx.x;
    const int lane = tid & 63;
    const int wv   = tid >> 6;
    const int blk  = blockIdx.x;
    const int tokbase = blk * 64 + wv * 16;

    for (int i = tid; i < KCB; i += 256) esq_lds[i] = esq[i];

    // A fragments: 16 tokens x K=512, f16 hi/lo, in registers
    // A[row][k]: row = lane&15, k = kc*32 + (lane>>4)*8 + j
    half8 zh[16], zl[16];
    {
        const float* zr = z + (size_t)(tokbase + (lane & 15)) * DIM + ((lane >> 4) << 3);
        #pragma unroll
        for (int kc = 0; kc < 16; ++kc) {
            float4 a = *(const float4*)(zr + kc * 32);
            float4 b = *(const float4*)(zr + kc * 32 + 4);
            float v[8] = {a.x, a.y, a.z, a.w, b.x, b.y, b.z, b.w};
            half8 h, l;
            #pragma unroll
            for (int j = 0; j < 8; ++j) {
                const _Float16 hv = (_Float16)v[j];
                h[j] = hv;
                l[j] = (_Float16)(v[j] - (float)hv);
            }
            zh[kc] = h; zl[kc] = l;
        }
    }

    // stage 16-code tile (f16 rows, 1024 B each); per-lane pre-swizzled
    // global source so swizzled LDS read is conflict-free (both-sides swz).
    auto STAGE = [&](int ch, int buf) {
        #pragma unroll
        for (int i = 0; i < 4; ++i) {
            const int c = (wv << 2) + i;
            const size_t grow = (size_t)((ch << 4) + c) * 512;
            const int soff = (lane ^ (c & 15)) << 3;   // f16 units (16B granules)
            __builtin_amdgcn_global_load_lds(
                (const __attribute__((address_space(1))) void*)(Ehf + grow + soff),
                (__attribute__((address_space(3))) void*)&ehi_t[buf][c * 512], 16, 0, 0);
        }
    };

    float d1[4], d2[4]; int i1[4];
    #pragma unroll
    for (int r = 0; r < 4; ++r) { d1[r] = FLT_MAX; d2[r] = FLT_MAX; i1[r] = KCB; }

    STAGE(0, 0);
    __syncthreads();   // full drain: chunk 0 + esq_lds + A-frags all resolved

    for (int ch = 0; ch < 64; ++ch) {
        const int cur = ch & 1;
        if (ch < 63) {
            STAGE(ch + 1, cur ^ 1);            // issue next tile (no wait)
            asm volatile("s_waitcnt vmcnt(4)" ::: "memory");  // chunk ch landed (own 4)
        } else {
            asm volatile("s_waitcnt vmcnt(0)" ::: "memory");
        }
        __builtin_amdgcn_sched_barrier(0);
        __builtin_amdgcn_s_barrier();          // all waves' chunk-ch stages landed
        __builtin_amdgcn_sched_barrier(0);

        f32x4 acc = {0.f, 0.f, 0.f, 0.f};
        #pragma unroll
        for (int kc = 0; kc < 16; ++kc) {
            // B[k][col]: col = lane&15 (code row), granule g = kc*4 + (lane>>4)
            const int g = (kc << 2) + (lane >> 4);
            const int u = g ^ (lane & 15);
            const int base = (lane & 15) * 512 + (u << 3);
            const half8 eh = *(const half8*)&ehi_t[cur][base];
            acc = __builtin_amdgcn_mfma_f32_16x16x32_f16(zh[kc], eh, acc, 0, 0, 0);
            acc = __builtin_amdgcn_mfma_f32_16x16x32_f16(zl[kc], eh, acc, 0, 0, 0);
        }

        // C/D layout: col = lane&15 -> code, row = (lane>>4)*4 + r -> token
        const int code = (ch << 4) + (lane & 15);
        const float ej = esq_lds[code];
        #pragma unroll
        for (int r = 0; r < 4; ++r) {
            const float dist = fmaf(-2.0f, acc[r], ej);
            if (dist < d1[r]) { d2[r] = d1[r]; d1[r] = dist; i1[r] = code; }
            else              { d2[r] = fminf(d2[r], dist); }
        }
        __builtin_amdgcn_sched_barrier(0);
        __builtin_amdgcn_s_barrier();          // all reads of buf[cur] done before
                                               // next iter's STAGE overwrites it
    }

    // merge top-2 across the 16 code-lanes (low 4 lane bits)
    #pragma unroll
    for (int off = 1; off < 16; off <<= 1) {
        #pragma unroll
        for (int r = 0; r < 4; ++r) {
            const float od1 = __shfl_xor(d1[r], off, 64);
            const int   oi1 = __shfl_xor(i1[r], off, 64);
            const float od2 = __shfl_xor(d2[r], off, 64);
            float loser;
            if (od1 < d1[r] || (od1 == d1[r] && oi1 < i1[r])) {
                loser = d1[r]; d1[r] = od1; i1[r] = oi1;
            } else {
                loser = od1;
            }
            d2[r] = fminf(fminf(d2[r], od2), loser);
        }
    }
    if ((lane & 15) == 0) {
        #pragma unroll
        for (int r = 0; r < 4; ++r) {
            const int token = tokbase + ((lane >> 4) << 2) + r;
            idx_ws[token]  = i1[r];
            idx_out[token] = (float)i1[r];
            if (d2[r] - d1[r] < TAU) {
                int slot = atomicAdd(refCount, 1);
                if (slot < REF_CAP) refList[slot] = token;
            }
        }
    }
}

// f64 exact re-scoring of near-tie tokens. 16 groups of 16 lanes per block;
// group owns a code (lane = 32 dims), 2 codes in flight, 4-level reduce.
__global__ __launch_bounds__(256) void refine_kernel(
    const float* __restrict__ z, const float* __restrict__ E,
    const int* __restrict__ refCount, const int* __restrict__ refList,
    int* __restrict__ idx_ws, float* __restrict__ idx_out)
{
    __shared__ double dists[KCB];
    const int tid = threadIdx.x;
    const int grp = tid >> 4;
    const int q   = tid & 15;
    int rc = *refCount; if (rc > REF_CAP) rc = REF_CAP;
    for (int r = blockIdx.x; r < rc; r += gridDim.x) {
        const int token = refList[r];
        double zr[32];
        {
            const float* zp = z + (size_t)token * DIM + q * 32;
            #pragma unroll
            for (int j = 0; j < 8; ++j) {
                const float4 v = *(const float4*)(zp + j * 4);
                zr[j*4+0] = (double)v.x; zr[j*4+1] = (double)v.y;
                zr[j*4+2] = (double)v.z; zr[j*4+3] = (double)v.w;
            }
        }
        for (int c = grp; c < KCB; c += 32) {
            const int c2 = c + 16;
            const float* ep  = E + (size_t)c  * DIM + q * 32;
            const float* ep2 = E + (size_t)c2 * DIM + q * 32;
            double s = 0.0, s2 = 0.0;
            #pragma unroll
            for (int j = 0; j < 8; ++j) {
                const float4 a = *(const float4*)(ep  + j * 4);
                const float4 b = *(const float4*)(ep2 + j * 4);
                double d;
                d = zr[j*4+0] - (double)a.x; s  = fma(d, d, s);
                d = zr[j*4+1] - (double)a.y; s  = fma(d, d, s);
                d = zr[j*4+2] - (double)a.z; s  = fma(d, d, s);
                d = zr[j*4+3] - (double)a.w; s  = fma(d, d, s);
                d = zr[j*4+0] - (double)b.x; s2 = fma(d, d, s2);
                d = zr[j*4+1] - (double)b.y; s2 = fma(d, d, s2);
                d = zr[j*4+2] - (double)b.z; s2 = fma(d, d, s2);
                d = zr[j*4+3] - (double)b.w; s2 = fma(d, d, s2);
            }
            #pragma unroll
            for (int off = 1; off < 16; off <<= 1) {
                s  += __shfl_xor(s,  off, 64);
                s2 += __shfl_xor(s2, off, 64);
            }
            if (q == 0) { dists[c] = s; dists[c2] = s2; }
        }
        __syncthreads();
        if (tid < 64) {
            const int lane = tid;
            double best = dists[lane]; int bi = lane;
            for (int c = lane + 64; c < KCB; c += 64) {
                const double dv = dists[c];
                if (dv < best) { best = dv; bi = c; }   // ascending: keeps lowest idx
            }
            for (int off = 32; off > 0; off >>= 1) {
                const double ob = __shfl_down(best, off, 64);
                const int    oi = __shfl_down(bi, off, 64);
                if (ob < best || (ob == best && oi < bi)) { best = ob; bi = oi; }
            }
            if (lane == 0) { idx_ws[token] = bi; idx_out[token] = (float)bi; }
        }
        __syncthreads();
    }
}

// ---- counting sort of tokens by code ----
__global__ __launch_bounds__(256) void hist_kernel(const int* __restrict__ idx,
                                                   int* __restrict__ counts)
{
    __shared__ int h[KCB];
    const int tid = threadIdx.x;
    for (int i = tid; i < KCB; i += 256) h[i] = 0;
    __syncthreads();
    const int b0 = blockIdx.x * 1024;
    #pragma unroll
    for (int j = 0; j < 4; ++j) atomicAdd(&h[idx[b0 + j * 256 + tid]], 1);
    __syncthreads();
    for (int i = tid; i < KCB; i += 256) {
        const int v = h[i];
        if (v) atomicAdd(&counts[i], v);
    }
}

__global__ __launch_bounds__(1024) void scan_kernel(const int* __restrict__ counts,
                                                    int* __restrict__ cursor,
                                                    int* __restrict__ base)
{
    const int tid = threadIdx.x, lane = tid & 63, wv = tid >> 6;
    const int v = counts[tid];
    int s = v;
    #pragma unroll
    for (int off = 1; off < 64; off <<= 1) {
        const int nb = __shfl_up(s, off, 64);
        if (lane >= off) s += nb;
    }
    __shared__ int wsum[16], wbase[16];
    if (lane == 63) wsum[wv] = s;
    __syncthreads();
    if (tid == 0) {
        int r = 0;
        for (int w = 0; w < 16; ++w) { wbase[w] = r; r += wsum[w]; }
    }
    __syncthreads();
    const int excl = wbase[wv] + s - v;
    cursor[tid] = excl;
    base[tid]   = excl;
}

__global__ __launch_bounds__(256) void scatter_kernel(const int* __restrict__ idx,
                                                      int* __restrict__ cursor,
                                                      int* __restrict__ toklist)
{
    const int b0 = blockIdx.x * 1024;
    #pragma unroll
    for (int j = 0; j < 4; ++j) {
        const int t = b0 + j * 256 + threadIdx.x;
        const int k = idx[t];
        const int slot = atomicAdd(&cursor[k], 1);
        toklist[slot] = t;
    }
}

// Uniform-work segment sum: block b owns sorted slots [b*64, b*64+64).
__global__ __launch_bounds__(256) void seg_sum_kernel(
    const float* __restrict__ z, const float* __restrict__ E,
    const int* __restrict__ toklist, const int* __restrict__ idx,
    float* __restrict__ out0, float* __restrict__ esum)
{
    __shared__ int toks[64];
    __shared__ int ks[64];
    const int tid  = threadIdx.x;
    const int seg0 = blockIdx.x * 64;
    if (tid < 64) toks[tid] = toklist[seg0 + tid];
    __syncthreads();
    if (tid < 64) ks[tid] = idx[toks[tid]];
    __syncthreads();

    const int d = tid * 2;
    int curk = ks[0];
    float2 er  = *(const float2*)(E + (size_t)curk * DIM + d);
    float2 acc = {0.f, 0.f};
    float2 v   = *(const float2*)(z + (size_t)toks[0] * DIM + d);
    for (int i = 0; i < 64; ++i) {
        const int t = toks[i];
        float2 vn;
        if (i < 63) vn = *(const float2*)(z + (size_t)toks[i + 1] * DIM + d);
        const int k = ks[i];
        if (k != curk) {                       // block-uniform branch (~2/segment)
            atomicAdd(&esum[(size_t)curk * DIM + d],     acc.x);
            atomicAdd(&esum[(size_t)curk * DIM + d + 1], acc.y);
            acc.x = 0.f; acc.y = 0.f;
            curk = k;
            er = *(const float2*)(E + (size_t)k * DIM + d);
        }
        *(float2*)(out0 + (size_t)t * DIM + d) = er;
        acc.x += v.x; acc.y += v.y;
        v = vn;
    }
    atomicAdd(&esum[(size_t)curk * DIM + d],     acc.x);
    atomicAdd(&esum[(size_t)curk * DIM + d + 1], acc.y);
}

__global__ __launch_bounds__(1024) void cs_n_kernel(const float* __restrict__ cs,
    const int* __restrict__ counts, float* __restrict__ out3,
    float* __restrict__ n_ws)
{
    const int k = threadIdx.x;
    const float ncs = 0.99f * cs[k] + 0.01f * (float)counts[k];
    out3[k] = ncs;
    float s = ncs;
    for (int off = 32; off > 0; off >>= 1) s += __shfl_down(s, off, 64);
    __shared__ float red[16];
    const int lane = k & 63, wv = k >> 6;
    if (lane == 0) red[wv] = s;
    __syncthreads();
    if (k == 0) {
        float t = 0.f;
        for (int i = 0; i < 16; ++i) t += red[i];
        n_ws[0] = t;
    }
}

__global__ __launch_bounds__(256) void out24_kernel(const float* __restrict__ ea,
    const float* __restrict__ esum, const float* __restrict__ out3,
    const float* __restrict__ n_ws, float* __restrict__ out2,
    float* __restrict__ out4)
{
    const size_t i = (size_t)blockIdx.x * 256 + threadIdx.x;
    const int k = (int)(i >> 9);
    const float n = n_ws[0];
    const float smoothed = (out3[k] + 1e-5f) / (n + 0.01024f) * n;
    const float nea = 0.99f * ea[i] + 0.01f * esum[i];
    out4[i] = nea;
    out2[i] = nea / smoothed;
}

extern "C" void kernel_launch(void* const* d_in, const int* in_sizes, int n_in,
                              void* d_out, int out_size, void* d_ws, size_t ws_size,
                              hipStream_t stream)
{
    const float* z  = (const float*)d_in[0];
    const float* E  = (const float*)d_in[1];
    const float* cs = (const float*)d_in[2];
    const float* ea = (const float*)d_in[3];

    float* out0 = (float*)d_out;                       // quantized_st [NTOK*DIM]
    float* out1 = out0 + (size_t)NTOK * DIM;           // indices (as f32) [NTOK]
    float* out2 = out1 + NTOK;                         // new_embedding [KCB*DIM]
    float* out3 = out2 + (size_t)KCB * DIM;            // new_cluster_size [KCB]
    float* out4 = out3 + KCB;                          // new_embed_avg [KCB*DIM]

    char* ws = (char*)d_ws;
    int*   idx_ws  = (int*)ws;
    float* esq     = (float*)(ws + 262144);
    int*   refCnt  = (int*)(ws + 266240);
    int*   refList = (int*)(ws + 266256);
    float* n_ws    = (float*)(ws + 282640);
    int*   counts  = (int*)(ws + 282656);
    int*   cursor  = (int*)(ws + 286752);
    int*   base    = (int*)(ws + 290848);
    u16*   Ehf     = (u16*)(ws + 294976);
    float* esum    = (float*)(ws + 294976);            // aliases Ehf (2 MB span)
    int*   toklist = (int*)out2;                       // out2 region as scratch

    hipMemsetAsync(refCnt, 0, sizeof(int), stream);
    hipMemsetAsync(counts, 0, KCB * sizeof(int), stream);

    esq_kernel<<<KCB / 4, 256, 0, stream>>>(E, esq);
    ehalf_kernel<<<(KCB * DIM / 2) / 256, 256, 0, stream>>>(E, Ehf);
    score_kernel<<<NTOK / 64, 256, 0, stream>>>(z, Ehf, esq, idx_ws, out1, refCnt, refList);
    // Ehf dead from here; zero esum over that region (stream-ordered)
    hipMemsetAsync(esum, 0, (size_t)KCB * DIM * sizeof(float), stream);
    refine_kernel<<<1024, 256, 0, stream>>>(z, E, refCnt, refList, idx_ws, out1);
    hist_kernel<<<NTOK / 1024, 256, 0, stream>>>(idx_ws, counts);
    scan_kernel<<<1, 1024, 0, stream>>>(counts, cursor, base);
    scatter_kernel<<<NTOK / 1024, 256, 0, stream>>>(idx_ws, cursor, toklist);
    seg_sum_kernel<<<NTOK / 64, 256, 0, stream>>>(z, E, toklist, idx_ws, out0, esum);
    cs_n_kernel<<<1, 1024, 0, stream>>>(cs, counts, out3, n_ws);
    out24_kernel<<<(KCB * DIM) / 256, 256, 0, stream>>>(ea, esum, out3, n_ws, out2, out4);
}

// Round 9
// 377.422 us; speedup vs baseline: 1.6228x; 1.4285x over previous
//
#include <hip/hip_runtime.h>
#include <cfloat>

#define NTOK 65536
#define DIM  512
#define KCB  1024
#define TAU  0.12f
#define REF_CAP 4096

typedef unsigned short u16;
typedef __attribute__((ext_vector_type(8))) _Float16 half8;
typedef __attribute__((ext_vector_type(4))) float f32x4;

// ---------------- ws layout (bytes) ----------------
// 0       : idx       int[NTOK]        262144
// 262144  : esq       f32[KCB]         4096    -> 266240
// 266240  : refCount  int (16B pad)            -> 266256
// 266256  : refList   int[REF_CAP]     16384   -> 282640
// 282640  : n         f32                      -> 282656 (pad)
// 282656  : counts    int[KCB]         4096    -> 286752
// 286752  : cursor    int[KCB]         4096    -> 290848
// 290848  : base      int[KCB]         4096    -> 294944
// 294976  : E_hf      f16[KCB*DIM]     1048576 -> 1343552
// esum f32[KCB*DIM] (2 MB) aliases E_hf.. (dead after score), end 2392128
// toklist int[NTOK] lives in d_out's out2 region (dead until out24_kernel)

__device__ __forceinline__ u16 h2u(_Float16 h) {
    u16 u; __builtin_memcpy(&u, &h, 2); return u;
}

__global__ __launch_bounds__(256) void esq_kernel(const float* __restrict__ E,
                                                  float* __restrict__ esq)
{
    const int lane = threadIdx.x & 63;
    const int wv   = threadIdx.x >> 6;
    const int k    = blockIdx.x * 4 + wv;
    const float* er = E + (size_t)k * DIM + lane * 8;
    float4 a = *(const float4*)er;
    float4 b = *(const float4*)(er + 4);
    float s = a.x*a.x + a.y*a.y + a.z*a.z + a.w*a.w
            + b.x*b.x + b.y*b.y + b.z*b.z + b.w*b.w;
    for (int off = 32; off > 0; off >>= 1) s += __shfl_down(s, off, 64);
    if (lane == 0) esq[k] = s;
}

// E -> f16 (RNE), row-major [KCB][DIM]
__global__ __launch_bounds__(256) void ehalf_kernel(const float* __restrict__ E,
                                                    u16* __restrict__ Ehf)
{
    const size_t i = (size_t)blockIdx.x * 256 + threadIdx.x;   // pair index
    const float2 v = *(const float2*)(E + i * 2);
    const _Float16 h0 = (_Float16)v.x, h1 = (_Float16)v.y;
    ((unsigned int*)Ehf)[i] = ((unsigned int)h2u(h1) << 16) | h2u(h0);
}

// Convert one f32 to f16 hi + f16 residual, all-static indices (rule #20)
#define CVT(ZH, ZL, J, VAL) { const _Float16 hv_ = (_Float16)(VAL); \
    (ZH)[J] = hv_; (ZL)[J] = (_Float16)((VAL) - (float)hv_); }

#define LOADK(KC, ZH, ZL) { \
    const float4 a_ = *(const float4*)(zr + (KC) * 32); \
    const float4 b_ = *(const float4*)(zr + (KC) * 32 + 4); \
    CVT(ZH, ZL, 0, a_.x) CVT(ZH, ZL, 1, a_.y) \
    CVT(ZH, ZL, 2, a_.z) CVT(ZH, ZL, 3, a_.w) \
    CVT(ZH, ZL, 4, b_.x) CVT(ZH, ZL, 5, b_.y) \
    CVT(ZH, ZL, 6, b_.z) CVT(ZH, ZL, 7, b_.w) }

// B-frag read: col = lo16 (code row), granule g = KC*4 + hi16, swz by lo16.
// accA: zh chain, accB: zl chain (independent -> 2x MFMA ILP)
#define KSTEP(KC, ZH, ZL) { \
    const int u_ = (((KC) << 2) + hi16) ^ lo16; \
    const half8 eh_ = *(const half8*)&ehi_t[lo16 * 512 + (u_ << 3)]; \
    accA = __builtin_amdgcn_mfma_f32_16x16x32_f16((ZH), eh_, accA, 0, 0, 0); \
    accB = __builtin_amdgcn_mfma_f32_16x16x32_f16((ZL), eh_, accB, 0, 0, 0); }

// MFMA split-f16 scoring: 64 tokens/block (16/wave, K=512 resident in
// named registers), 64 chunks of 16 codes staged via global_load_lds.
__global__ __launch_bounds__(256, 2) void score_kernel(
    const float* __restrict__ z,
    const u16* __restrict__ Ehf,
    const float* __restrict__ esq,
    int* __restrict__ idx_ws, float* __restrict__ idx_out,
    int* __restrict__ refCount, int* __restrict__ refList)
{
    __shared__ _Float16 ehi_t[16 * 512];   // 16 KB, granule-swizzled rows
    __shared__ float esq_lds[KCB];         // 4 KB

    const int tid  = threadIdx.x;
    const int lane = tid & 63;
    const int wv   = tid >> 6;
    const int lo16 = lane & 15;
    const int hi16 = lane >> 4;
    const int blk  = blockIdx.x;
    const int tokbase = blk * 64 + wv * 16;

    for (int i = tid; i < KCB; i += 256) esq_lds[i] = esq[i];

    // A fragments: 16 tokens x K=512, f16 hi/lo, in NAMED registers.
    // A[row][k]: row = lo16, k = kc*32 + hi16*8 + j
    const float* zr = z + (size_t)(tokbase + lo16) * DIM + (hi16 << 3);
    half8 zh0,zh1,zh2,zh3,zh4,zh5,zh6,zh7,zh8,zh9,zh10,zh11,zh12,zh13,zh14,zh15;
    half8 zl0,zl1,zl2,zl3,zl4,zl5,zl6,zl7,zl8,zl9,zl10,zl11,zl12,zl13,zl14,zl15;
    LOADK(0,  zh0,  zl0)  LOADK(1,  zh1,  zl1)  LOADK(2,  zh2,  zl2)
    LOADK(3,  zh3,  zl3)  LOADK(4,  zh4,  zl4)  LOADK(5,  zh5,  zl5)
    LOADK(6,  zh6,  zl6)  LOADK(7,  zh7,  zl7)  LOADK(8,  zh8,  zl8)
    LOADK(9,  zh9,  zl9)  LOADK(10, zh10, zl10) LOADK(11, zh11, zl11)
    LOADK(12, zh12, zl12) LOADK(13, zh13, zl13) LOADK(14, zh14, zl14)
    LOADK(15, zh15, zl15)

    float d1[4], d2[4]; int i1[4];
    #pragma unroll
    for (int r = 0; r < 4; ++r) { d1[r] = FLT_MAX; d2[r] = FLT_MAX; i1[r] = KCB; }

    for (int ch = 0; ch < 64; ++ch) {
        __syncthreads();   // previous chunk's reads done before overwrite
        // stage 16-code tile (f16 rows, 1024 B each); per-lane pre-swizzled
        // global source so the swizzled LDS read is conflict-free.
        #pragma unroll
        for (int i = 0; i < 4; ++i) {
            const int c = (wv << 2) + i;
            const size_t grow = (size_t)((ch << 4) + c) * 512;
            const int soff = (lane ^ (c & 15)) << 3;   // f16 units (16B granules)
            __builtin_amdgcn_global_load_lds(
                (const __attribute__((address_space(1))) void*)(Ehf + grow + soff),
                (__attribute__((address_space(3))) void*)&ehi_t[c * 512], 16, 0, 0);
        }
        __syncthreads();   // drains vmcnt: tile ready

        f32x4 accA = {0.f, 0.f, 0.f, 0.f};
        f32x4 accB = {0.f, 0.f, 0.f, 0.f};
        KSTEP(0,  zh0,  zl0)  KSTEP(1,  zh1,  zl1)  KSTEP(2,  zh2,  zl2)
        KSTEP(3,  zh3,  zl3)  KSTEP(4,  zh4,  zl4)  KSTEP(5,  zh5,  zl5)
        KSTEP(6,  zh6,  zl6)  KSTEP(7,  zh7,  zl7)  KSTEP(8,  zh8,  zl8)
        KSTEP(9,  zh9,  zl9)  KSTEP(10, zh10, zl10) KSTEP(11, zh11, zl11)
        KSTEP(12, zh12, zl12) KSTEP(13, zh13, zl13) KSTEP(14, zh14, zl14)
        KSTEP(15, zh15, zl15)

        // C/D layout: col = lo16 -> code, row = hi16*4 + r -> token
        const int code = (ch << 4) + lo16;
        const float ej = esq_lds[code];
        #pragma unroll
        for (int r = 0; r < 4; ++r) {
            const float dist = fmaf(-2.0f, accA[r] + accB[r], ej);
            if (dist < d1[r]) { d2[r] = d1[r]; d1[r] = dist; i1[r] = code; }
            else              { d2[r] = fminf(d2[r], dist); }
        }
    }

    // merge top-2 across the 16 code-lanes (low 4 lane bits)
    #pragma unroll
    for (int off = 1; off < 16; off <<= 1) {
        #pragma unroll
        for (int r = 0; r < 4; ++r) {
            const float od1 = __shfl_xor(d1[r], off, 64);
            const int   oi1 = __shfl_xor(i1[r], off, 64);
            const float od2 = __shfl_xor(d2[r], off, 64);
            float loser;
            if (od1 < d1[r] || (od1 == d1[r] && oi1 < i1[r])) {
                loser = d1[r]; d1[r] = od1; i1[r] = oi1;
            } else {
                loser = od1;
            }
            d2[r] = fminf(fminf(d2[r], od2), loser);
        }
    }
    if (lo16 == 0) {
        #pragma unroll
        for (int r = 0; r < 4; ++r) {
            const int token = tokbase + (hi16 << 2) + r;
            idx_ws[token]  = i1[r];
            idx_out[token] = (float)i1[r];
            if (d2[r] - d1[r] < TAU) {
                int slot = atomicAdd(refCount, 1);
                if (slot < REF_CAP) refList[slot] = token;
            }
        }
    }
}

// f64 exact re-scoring of near-tie tokens. 16 groups of 16 lanes per block;
// group owns a code (lane = 32 dims), 2 codes in flight, 4-level reduce.
__global__ __launch_bounds__(256) void refine_kernel(
    const float* __restrict__ z, const float* __restrict__ E,
    const int* __restrict__ refCount, const int* __restrict__ refList,
    int* __restrict__ idx_ws, float* __restrict__ idx_out)
{
    __shared__ double dists[KCB];
    const int tid = threadIdx.x;
    const int grp = tid >> 4;
    const int q   = tid & 15;
    int rc = *refCount; if (rc > REF_CAP) rc = REF_CAP;
    for (int r = blockIdx.x; r < rc; r += gridDim.x) {
        const int token = refList[r];
        double zr[32];
        {
            const float* zp = z + (size_t)token * DIM + q * 32;
            #pragma unroll
            for (int j = 0; j < 8; ++j) {
                const float4 v = *(const float4*)(zp + j * 4);
                zr[j*4+0] = (double)v.x; zr[j*4+1] = (double)v.y;
                zr[j*4+2] = (double)v.z; zr[j*4+3] = (double)v.w;
            }
        }
        for (int c = grp; c < KCB; c += 32) {
            const int c2 = c + 16;
            const float* ep  = E + (size_t)c  * DIM + q * 32;
            const float* ep2 = E + (size_t)c2 * DIM + q * 32;
            double s = 0.0, s2 = 0.0;
            #pragma unroll
            for (int j = 0; j < 8; ++j) {
                const float4 a = *(const float4*)(ep  + j * 4);
                const float4 b = *(const float4*)(ep2 + j * 4);
                double d;
                d = zr[j*4+0] - (double)a.x; s  = fma(d, d, s);
                d = zr[j*4+1] - (double)a.y; s  = fma(d, d, s);
                d = zr[j*4+2] - (double)a.z; s  = fma(d, d, s);
                d = zr[j*4+3] - (double)a.w; s  = fma(d, d, s);
                d = zr[j*4+0] - (double)b.x; s2 = fma(d, d, s2);
                d = zr[j*4+1] - (double)b.y; s2 = fma(d, d, s2);
                d = zr[j*4+2] - (double)b.z; s2 = fma(d, d, s2);
                d = zr[j*4+3] - (double)b.w; s2 = fma(d, d, s2);
            }
            #pragma unroll
            for (int off = 1; off < 16; off <<= 1) {
                s  += __shfl_xor(s,  off, 64);
                s2 += __shfl_xor(s2, off, 64);
            }
            if (q == 0) { dists[c] = s; dists[c2] = s2; }
        }
        __syncthreads();
        if (tid < 64) {
            const int lane = tid;
            double best = dists[lane]; int bi = lane;
            for (int c = lane + 64; c < KCB; c += 64) {
                const double dv = dists[c];
                if (dv < best) { best = dv; bi = c; }   // ascending: keeps lowest idx
            }
            for (int off = 32; off > 0; off >>= 1) {
                const double ob = __shfl_down(best, off, 64);
                const int    oi = __shfl_down(bi, off, 64);
                if (ob < best || (ob == best && oi < bi)) { best = ob; bi = oi; }
            }
            if (lane == 0) { idx_ws[token] = bi; idx_out[token] = (float)bi; }
        }
        __syncthreads();
    }
}

// ---- counting sort of tokens by code ----
__global__ __launch_bounds__(256) void hist_kernel(const int* __restrict__ idx,
                                                   int* __restrict__ counts)
{
    __shared__ int h[KCB];
    const int tid = threadIdx.x;
    for (int i = tid; i < KCB; i += 256) h[i] = 0;
    __syncthreads();
    const int b0 = blockIdx.x * 1024;
    #pragma unroll
    for (int j = 0; j < 4; ++j) atomicAdd(&h[idx[b0 + j * 256 + tid]], 1);
    __syncthreads();
    for (int i = tid; i < KCB; i += 256) {
        const int v = h[i];
        if (v) atomicAdd(&counts[i], v);
    }
}

__global__ __launch_bounds__(1024) void scan_kernel(const int* __restrict__ counts,
                                                    int* __restrict__ cursor,
                                                    int* __restrict__ base)
{
    const int tid = threadIdx.x, lane = tid & 63, wv = tid >> 6;
    const int v = counts[tid];
    int s = v;
    #pragma unroll
    for (int off = 1; off < 64; off <<= 1) {
        const int nb = __shfl_up(s, off, 64);
        if (lane >= off) s += nb;
    }
    __shared__ int wsum[16], wbase[16];
    if (lane == 63) wsum[wv] = s;
    __syncthreads();
    if (tid == 0) {
        int r = 0;
        for (int w = 0; w < 16; ++w) { wbase[w] = r; r += wsum[w]; }
    }
    __syncthreads();
    const int excl = wbase[wv] + s - v;
    cursor[tid] = excl;
    base[tid]   = excl;
}

__global__ __launch_bounds__(256) void scatter_kernel(const int* __restrict__ idx,
                                                      int* __restrict__ cursor,
                                                      int* __restrict__ toklist)
{
    const int b0 = blockIdx.x * 1024;
    #pragma unroll
    for (int j = 0; j < 4; ++j) {
        const int t = b0 + j * 256 + threadIdx.x;
        const int k = idx[t];
        const int slot = atomicAdd(&cursor[k], 1);
        toklist[slot] = t;
    }
}

// Uniform-work segment sum: block b owns sorted slots [b*64, b*64+64).
__global__ __launch_bounds__(256) void seg_sum_kernel(
    const float* __restrict__ z, const float* __restrict__ E,
    const int* __restrict__ toklist, const int* __restrict__ idx,
    float* __restrict__ out0, float* __restrict__ esum)
{
    __shared__ int toks[64];
    __shared__ int ks[64];
    const int tid  = threadIdx.x;
    const int seg0 = blockIdx.x * 64;
    if (tid < 64) toks[tid] = toklist[seg0 + tid];
    __syncthreads();
    if (tid < 64) ks[tid] = idx[toks[tid]];
    __syncthreads();

    const int d = tid * 2;
    int curk = ks[0];
    float2 er  = *(const float2*)(E + (size_t)curk * DIM + d);
    float2 acc = {0.f, 0.f};
    float2 v   = *(const float2*)(z + (size_t)toks[0] * DIM + d);
    for (int i = 0; i < 64; ++i) {
        const int t = toks[i];
        float2 vn;
        if (i < 63) vn = *(const float2*)(z + (size_t)toks[i + 1] * DIM + d);
        const int k = ks[i];
        if (k != curk) {                       // block-uniform branch (~2/segment)
            atomicAdd(&esum[(size_t)curk * DIM + d],     acc.x);
            atomicAdd(&esum[(size_t)curk * DIM + d + 1], acc.y);
            acc.x = 0.f; acc.y = 0.f;
            curk = k;
            er = *(const float2*)(E + (size_t)k * DIM + d);
        }
        *(float2*)(out0 + (size_t)t * DIM + d) = er;
        acc.x += v.x; acc.y += v.y;
        v = vn;
    }
    atomicAdd(&esum[(size_t)curk * DIM + d],     acc.x);
    atomicAdd(&esum[(size_t)curk * DIM + d + 1], acc.y);
}

__global__ __launch_bounds__(1024) void cs_n_kernel(const float* __restrict__ cs,
    const int* __restrict__ counts, float* __restrict__ out3,
    float* __restrict__ n_ws)
{
    const int k = threadIdx.x;
    const float ncs = 0.99f * cs[k] + 0.01f * (float)counts[k];
    out3[k] = ncs;
    float s = ncs;
    for (int off = 32; off > 0; off >>= 1) s += __shfl_down(s, off, 64);
    __shared__ float red[16];
    const int lane = k & 63, wv = k >> 6;
    if (lane == 0) red[wv] = s;
    __syncthreads();
    if (k == 0) {
        float t = 0.f;
        for (int i = 0; i < 16; ++i) t += red[i];
        n_ws[0] = t;
    }
}

__global__ __launch_bounds__(256) void out24_kernel(const float* __restrict__ ea,
    const float* __restrict__ esum, const float* __restrict__ out3,
    const float* __restrict__ n_ws, float* __restrict__ out2,
    float* __restrict__ out4)
{
    const size_t i = (size_t)blockIdx.x * 256 + threadIdx.x;
    const int k = (int)(i >> 9);
    const float n = n_ws[0];
    const float smoothed = (out3[k] + 1e-5f) / (n + 0.01024f) * n;
    const float nea = 0.99f * ea[i] + 0.01f * esum[i];
    out4[i] = nea;
    out2[i] = nea / smoothed;
}

extern "C" void kernel_launch(void* const* d_in, const int* in_sizes, int n_in,
                              void* d_out, int out_size, void* d_ws, size_t ws_size,
                              hipStream_t stream)
{
    const float* z  = (const float*)d_in[0];
    const float* E  = (const float*)d_in[1];
    const float* cs = (const float*)d_in[2];
    const float* ea = (const float*)d_in[3];

    float* out0 = (float*)d_out;                       // quantized_st [NTOK*DIM]
    float* out1 = out0 + (size_t)NTOK * DIM;           // indices (as f32) [NTOK]
    float* out2 = out1 + NTOK;                         // new_embedding [KCB*DIM]
    float* out3 = out2 + (size_t)KCB * DIM;            // new_cluster_size [KCB]
    float* out4 = out3 + KCB;                          // new_embed_avg [KCB*DIM]

    char* ws = (char*)d_ws;
    int*   idx_ws  = (int*)ws;
    float* esq     = (float*)(ws + 262144);
    int*   refCnt  = (int*)(ws + 266240);
    int*   refList = (int*)(ws + 266256);
    float* n_ws    = (float*)(ws + 282640);
    int*   counts  = (int*)(ws + 282656);
    int*   cursor  = (int*)(ws + 286752);
    int*   base    = (int*)(ws + 290848);
    u16*   Ehf     = (u16*)(ws + 294976);
    float* esum    = (float*)(ws + 294976);            // aliases Ehf (2 MB span)
    int*   toklist = (int*)out2;                       // out2 region as scratch

    hipMemsetAsync(refCnt, 0, sizeof(int), stream);
    hipMemsetAsync(counts, 0, KCB * sizeof(int), stream);

    esq_kernel<<<KCB / 4, 256, 0, stream>>>(E, esq);
    ehalf_kernel<<<(KCB * DIM / 2) / 256, 256, 0, stream>>>(E, Ehf);
    score_kernel<<<NTOK / 64, 256, 0, stream>>>(z, Ehf, esq, idx_ws, out1, refCnt, refList);
    // Ehf dead from here; zero esum over that region (stream-ordered)
    hipMemsetAsync(esum, 0, (size_t)KCB * DIM * sizeof(float), stream);
    refine_kernel<<<1024, 256, 0, stream>>>(z, E, refCnt, refList, idx_ws, out1);
    hist_kernel<<<NTOK / 1024, 256, 0, stream>>>(idx_ws, counts);
    scan_kernel<<<1, 1024, 0, stream>>>(counts, cursor, base);
    scatter_kernel<<<NTOK / 1024, 256, 0, stream>>>(idx_ws, cursor, toklist);
    seg_sum_kernel<<<NTOK / 64, 256, 0, stream>>>(z, E, toklist, idx_ws, out0, esum);
    cs_n_kernel<<<1, 1024, 0, stream>>>(cs, counts, out3, n_ws);
    out24_kernel<<<(KCB * DIM) / 256, 256, 0, stream>>>(ea, esum, out3, n_ws, out2, out4);
}

// Round 10
// 374.710 us; speedup vs baseline: 1.6345x; 1.0072x over previous
//
#include <hip/hip_runtime.h>
#include <cfloat>

#define NTOK 65536
#define DIM  512
#define KCB  1024
#define TAU  0.12f
#define REF_CAP 4096

typedef unsigned short u16;
typedef __attribute__((ext_vector_type(8))) _Float16 half8;
typedef __attribute__((ext_vector_type(4))) float f32x4;

// ---------------- ws layout (bytes) ----------------
// 0       : idx       int[NTOK]        262144
// 262144  : esq       f32[KCB]         4096    -> 266240
// 266240  : refCount  int (16B pad)            -> 266256
// 266256  : refList   int[REF_CAP]     16384   -> 282640
// 282640  : n         f32                      -> 282656 (pad)
// 282656  : counts    int[KCB]         4096    -> 286752
// 286752  : cursor    int[KCB]         4096    -> 290848
// 290848  : base      int[KCB]         4096    -> 294944
// 294976  : E_hf      f16[KCB*DIM]     1048576 -> 1343552
// esum f32[KCB*DIM] (2 MB) aliases E_hf.. (dead after score), end 2392128
// toklist int[NTOK] lives in d_out's out2 region (dead until out24_kernel)

__device__ __forceinline__ u16 h2u(_Float16 h) {
    u16 u; __builtin_memcpy(&u, &h, 2); return u;
}

__global__ __launch_bounds__(256) void esq_kernel(const float* __restrict__ E,
                                                  float* __restrict__ esq)
{
    const int lane = threadIdx.x & 63;
    const int wv   = threadIdx.x >> 6;
    const int k    = blockIdx.x * 4 + wv;
    const float* er = E + (size_t)k * DIM + lane * 8;
    float4 a = *(const float4*)er;
    float4 b = *(const float4*)(er + 4);
    float s = a.x*a.x + a.y*a.y + a.z*a.z + a.w*a.w
            + b.x*b.x + b.y*b.y + b.z*b.z + b.w*b.w;
    for (int off = 32; off > 0; off >>= 1) s += __shfl_down(s, off, 64);
    if (lane == 0) esq[k] = s;
}

// E -> f16 (RNE), row-major [KCB][DIM]
__global__ __launch_bounds__(256) void ehalf_kernel(const float* __restrict__ E,
                                                    u16* __restrict__ Ehf)
{
    const size_t i = (size_t)blockIdx.x * 256 + threadIdx.x;   // pair index
    const float2 v = *(const float2*)(E + i * 2);
    const _Float16 h0 = (_Float16)v.x, h1 = (_Float16)v.y;
    ((unsigned int*)Ehf)[i] = ((unsigned int)h2u(h1) << 16) | h2u(h0);
}

// Convert one f32 to f16 hi + f16 residual, all-static indices (rule #20)
#define CVT(ZH, ZL, J, VAL) { const _Float16 hv_ = (_Float16)(VAL); \
    (ZH)[J] = hv_; (ZL)[J] = (_Float16)((VAL) - (float)hv_); }

#define LOADK(KC, ZH, ZL) { \
    const float4 a_ = *(const float4*)(zr + (KC) * 32); \
    const float4 b_ = *(const float4*)(zr + (KC) * 32 + 4); \
    CVT(ZH, ZL, 0, a_.x) CVT(ZH, ZL, 1, a_.y) \
    CVT(ZH, ZL, 2, a_.z) CVT(ZH, ZL, 3, a_.w) \
    CVT(ZH, ZL, 4, b_.x) CVT(ZH, ZL, 5, b_.y) \
    CVT(ZH, ZL, 6, b_.z) CVT(ZH, ZL, 7, b_.w) }

// B-frag read: col = lo16 (code row), granule g = KC*4 + hi16, swz by lo16.
// accA: zh chain, accB: zl chain (independent -> 2x MFMA ILP)
#define KSTEP(KC, ZH, ZL) { \
    const int u_ = (((KC) << 2) + hi16) ^ lo16; \
    const half8 eh_ = *(const half8*)&bp[lo16 * 512 + (u_ << 3)]; \
    accA = __builtin_amdgcn_mfma_f32_16x16x32_f16((ZH), eh_, accA, 0, 0, 0); \
    accB = __builtin_amdgcn_mfma_f32_16x16x32_f16((ZL), eh_, accB, 0, 0, 0); }

// MFMA split-f16 scoring: 64 tokens/block (16/wave, K=512 resident in
// named registers); 64 chunks of 16 codes, double-buffered LDS with
// counted vmcnt (T3/T4): next-chunk loads stay in flight across barriers.
__global__ __launch_bounds__(256, 2) void score_kernel(
    const float* __restrict__ z,
    const u16* __restrict__ Ehf,
    const float* __restrict__ esq,
    int* __restrict__ idx_ws, float* __restrict__ idx_out,
    int* __restrict__ refCount, int* __restrict__ refList)
{
    __shared__ _Float16 ehi_t[2][16 * 512];   // 2 x 16 KB, granule-swizzled rows
    __shared__ float esq_lds[KCB];            // 4 KB

    const int tid  = threadIdx.x;
    const int lane = tid & 63;
    const int wv   = tid >> 6;
    const int lo16 = lane & 15;
    const int hi16 = lane >> 4;
    const int blk  = blockIdx.x;
    const int tokbase = blk * 64 + wv * 16;

    for (int i = tid; i < KCB; i += 256) esq_lds[i] = esq[i];

    // A fragments: 16 tokens x K=512, f16 hi/lo, in NAMED registers.
    // A[row][k]: row = lo16, k = kc*32 + hi16*8 + j
    const float* zr = z + (size_t)(tokbase + lo16) * DIM + (hi16 << 3);
    half8 zh0,zh1,zh2,zh3,zh4,zh5,zh6,zh7,zh8,zh9,zh10,zh11,zh12,zh13,zh14,zh15;
    half8 zl0,zl1,zl2,zl3,zl4,zl5,zl6,zl7,zl8,zl9,zl10,zl11,zl12,zl13,zl14,zl15;
    LOADK(0,  zh0,  zl0)  LOADK(1,  zh1,  zl1)  LOADK(2,  zh2,  zl2)
    LOADK(3,  zh3,  zl3)  LOADK(4,  zh4,  zl4)  LOADK(5,  zh5,  zl5)
    LOADK(6,  zh6,  zl6)  LOADK(7,  zh7,  zl7)  LOADK(8,  zh8,  zl8)
    LOADK(9,  zh9,  zl9)  LOADK(10, zh10, zl10) LOADK(11, zh11, zl11)
    LOADK(12, zh12, zl12) LOADK(13, zh13, zl13) LOADK(14, zh14, zl14)
    LOADK(15, zh15, zl15)

    // stage 16-code tile (f16 rows, 1024 B each); per-lane pre-swizzled
    // global source so the swizzled LDS read is conflict-free.
    auto STAGE = [&](int ch, int buf) {
        #pragma unroll
        for (int i = 0; i < 4; ++i) {
            const int c = (wv << 2) + i;
            const size_t grow = (size_t)((ch << 4) + c) * 512;
            const int soff = (lane ^ (c & 15)) << 3;   // f16 units (16B granules)
            __builtin_amdgcn_global_load_lds(
                (const __attribute__((address_space(1))) void*)(Ehf + grow + soff),
                (__attribute__((address_space(3))) void*)&ehi_t[buf][c * 512], 16, 0, 0);
        }
    };

    float d1[4], d2[4]; int i1[4];
    #pragma unroll
    for (int r = 0; r < 4; ++r) { d1[r] = FLT_MAX; d2[r] = FLT_MAX; i1[r] = KCB; }

    STAGE(0, 0);
    __syncthreads();   // full drain: chunk 0 + esq_lds + A-frags resolved

    for (int ch = 0; ch < 64; ++ch) {
        const int cur = ch & 1;
        if (ch < 63) {
            STAGE(ch + 1, cur ^ 1);            // issue next tile (no wait)
            asm volatile("s_waitcnt vmcnt(4)" ::: "memory");  // cur tile landed (own 4)
        } else {
            asm volatile("s_waitcnt vmcnt(0)" ::: "memory");
        }
        __builtin_amdgcn_sched_barrier(0);
        __builtin_amdgcn_s_barrier();          // all waves' cur-tile stages landed
        __builtin_amdgcn_sched_barrier(0);

        const _Float16* bp = ehi_t[cur];
        f32x4 accA = {0.f, 0.f, 0.f, 0.f};
        f32x4 accB = {0.f, 0.f, 0.f, 0.f};
        KSTEP(0,  zh0,  zl0)  KSTEP(1,  zh1,  zl1)  KSTEP(2,  zh2,  zl2)
        KSTEP(3,  zh3,  zl3)  KSTEP(4,  zh4,  zl4)  KSTEP(5,  zh5,  zl5)
        KSTEP(6,  zh6,  zl6)  KSTEP(7,  zh7,  zl7)  KSTEP(8,  zh8,  zl8)
        KSTEP(9,  zh9,  zl9)  KSTEP(10, zh10, zl10) KSTEP(11, zh11, zl11)
        KSTEP(12, zh12, zl12) KSTEP(13, zh13, zl13) KSTEP(14, zh14, zl14)
        KSTEP(15, zh15, zl15)

        // C/D layout: col = lo16 -> code, row = hi16*4 + r -> token
        const int code = (ch << 4) + lo16;
        const float ej = esq_lds[code];
        #pragma unroll
        for (int r = 0; r < 4; ++r) {
            const float dist = fmaf(-2.0f, accA[r] + accB[r], ej);
            if (dist < d1[r]) { d2[r] = d1[r]; d1[r] = dist; i1[r] = code; }
            else              { d2[r] = fminf(d2[r], dist); }
        }
        __builtin_amdgcn_sched_barrier(0);
        __builtin_amdgcn_s_barrier();          // reads of buf[cur] done before
                                               // next iter's STAGE overwrites it
        __builtin_amdgcn_sched_barrier(0);
    }

    // merge top-2 across the 16 code-lanes (low 4 lane bits)
    #pragma unroll
    for (int off = 1; off < 16; off <<= 1) {
        #pragma unroll
        for (int r = 0; r < 4; ++r) {
            const float od1 = __shfl_xor(d1[r], off, 64);
            const int   oi1 = __shfl_xor(i1[r], off, 64);
            const float od2 = __shfl_xor(d2[r], off, 64);
            float loser;
            if (od1 < d1[r] || (od1 == d1[r] && oi1 < i1[r])) {
                loser = d1[r]; d1[r] = od1; i1[r] = oi1;
            } else {
                loser = od1;
            }
            d2[r] = fminf(fminf(d2[r], od2), loser);
        }
    }
    if (lo16 == 0) {
        #pragma unroll
        for (int r = 0; r < 4; ++r) {
            const int token = tokbase + (hi16 << 2) + r;
            idx_ws[token]  = i1[r];
            idx_out[token] = (float)i1[r];
            if (d2[r] - d1[r] < TAU) {
                int slot = atomicAdd(refCount, 1);
                if (slot < REF_CAP) refList[slot] = token;
            }
        }
    }
}

// f64 exact re-scoring of near-tie tokens. 16 groups of 16 lanes per block;
// group owns a code (lane = 32 dims), 2 codes in flight, 4-level reduce.
__global__ __launch_bounds__(256) void refine_kernel(
    const float* __restrict__ z, const float* __restrict__ E,
    const int* __restrict__ refCount, const int* __restrict__ refList,
    int* __restrict__ idx_ws, float* __restrict__ idx_out)
{
    __shared__ double dists[KCB];
    const int tid = threadIdx.x;
    const int grp = tid >> 4;
    const int q   = tid & 15;
    int rc = *refCount; if (rc > REF_CAP) rc = REF_CAP;
    for (int r = blockIdx.x; r < rc; r += gridDim.x) {
        const int token = refList[r];
        double zr[32];
        {
            const float* zp = z + (size_t)token * DIM + q * 32;
            #pragma unroll
            for (int j = 0; j < 8; ++j) {
                const float4 v = *(const float4*)(zp + j * 4);
                zr[j*4+0] = (double)v.x; zr[j*4+1] = (double)v.y;
                zr[j*4+2] = (double)v.z; zr[j*4+3] = (double)v.w;
            }
        }
        for (int c = grp; c < KCB; c += 32) {
            const int c2 = c + 16;
            const float* ep  = E + (size_t)c  * DIM + q * 32;
            const float* ep2 = E + (size_t)c2 * DIM + q * 32;
            double s = 0.0, s2 = 0.0;
            #pragma unroll
            for (int j = 0; j < 8; ++j) {
                const float4 a = *(const float4*)(ep  + j * 4);
                const float4 b = *(const float4*)(ep2 + j * 4);
                double d;
                d = zr[j*4+0] - (double)a.x; s  = fma(d, d, s);
                d = zr[j*4+1] - (double)a.y; s  = fma(d, d, s);
                d = zr[j*4+2] - (double)a.z; s  = fma(d, d, s);
                d = zr[j*4+3] - (double)a.w; s  = fma(d, d, s);
                d = zr[j*4+0] - (double)b.x; s2 = fma(d, d, s2);
                d = zr[j*4+1] - (double)b.y; s2 = fma(d, d, s2);
                d = zr[j*4+2] - (double)b.z; s2 = fma(d, d, s2);
                d = zr[j*4+3] - (double)b.w; s2 = fma(d, d, s2);
            }
            #pragma unroll
            for (int off = 1; off < 16; off <<= 1) {
                s  += __shfl_xor(s,  off, 64);
                s2 += __shfl_xor(s2, off, 64);
            }
            if (q == 0) { dists[c] = s; dists[c2] = s2; }
        }
        __syncthreads();
        if (tid < 64) {
            const int lane = tid;
            double best = dists[lane]; int bi = lane;
            for (int c = lane + 64; c < KCB; c += 64) {
                const double dv = dists[c];
                if (dv < best) { best = dv; bi = c; }   // ascending: keeps lowest idx
            }
            for (int off = 32; off > 0; off >>= 1) {
                const double ob = __shfl_down(best, off, 64);
                const int    oi = __shfl_down(bi, off, 64);
                if (ob < best || (ob == best && oi < bi)) { best = ob; bi = oi; }
            }
            if (lane == 0) { idx_ws[token] = bi; idx_out[token] = (float)bi; }
        }
        __syncthreads();
    }
}

// ---- counting sort of tokens by code ----
__global__ __launch_bounds__(256) void hist_kernel(const int* __restrict__ idx,
                                                   int* __restrict__ counts)
{
    __shared__ int h[KCB];
    const int tid = threadIdx.x;
    for (int i = tid; i < KCB; i += 256) h[i] = 0;
    __syncthreads();
    const int b0 = blockIdx.x * 1024;
    #pragma unroll
    for (int j = 0; j < 4; ++j) atomicAdd(&h[idx[b0 + j * 256 + tid]], 1);
    __syncthreads();
    for (int i = tid; i < KCB; i += 256) {
        const int v = h[i];
        if (v) atomicAdd(&counts[i], v);
    }
}

__global__ __launch_bounds__(1024) void scan_kernel(const int* __restrict__ counts,
                                                    int* __restrict__ cursor,
                                                    int* __restrict__ base)
{
    const int tid = threadIdx.x, lane = tid & 63, wv = tid >> 6;
    const int v = counts[tid];
    int s = v;
    #pragma unroll
    for (int off = 1; off < 64; off <<= 1) {
        const int nb = __shfl_up(s, off, 64);
        if (lane >= off) s += nb;
    }
    __shared__ int wsum[16], wbase[16];
    if (lane == 63) wsum[wv] = s;
    __syncthreads();
    if (tid == 0) {
        int r = 0;
        for (int w = 0; w < 16; ++w) { wbase[w] = r; r += wsum[w]; }
    }
    __syncthreads();
    const int excl = wbase[wv] + s - v;
    cursor[tid] = excl;
    base[tid]   = excl;
}

__global__ __launch_bounds__(256) void scatter_kernel(const int* __restrict__ idx,
                                                      int* __restrict__ cursor,
                                                      int* __restrict__ toklist)
{
    const int b0 = blockIdx.x * 1024;
    #pragma unroll
    for (int j = 0; j < 4; ++j) {
        const int t = b0 + j * 256 + threadIdx.x;
        const int k = idx[t];
        const int slot = atomicAdd(&cursor[k], 1);
        toklist[slot] = t;
    }
}

// Uniform-work segment sum: block b owns sorted slots [b*64, b*64+64).
__global__ __launch_bounds__(256) void seg_sum_kernel(
    const float* __restrict__ z, const float* __restrict__ E,
    const int* __restrict__ toklist, const int* __restrict__ idx,
    float* __restrict__ out0, float* __restrict__ esum)
{
    __shared__ int toks[64];
    __shared__ int ks[64];
    const int tid  = threadIdx.x;
    const int seg0 = blockIdx.x * 64;
    if (tid < 64) toks[tid] = toklist[seg0 + tid];
    __syncthreads();
    if (tid < 64) ks[tid] = idx[toks[tid]];
    __syncthreads();

    const int d = tid * 2;
    int curk = ks[0];
    float2 er  = *(const float2*)(E + (size_t)curk * DIM + d);
    float2 acc = {0.f, 0.f};
    float2 v   = *(const float2*)(z + (size_t)toks[0] * DIM + d);
    for (int i = 0; i < 64; ++i) {
        const int t = toks[i];
        float2 vn;
        if (i < 63) vn = *(const float2*)(z + (size_t)toks[i + 1] * DIM + d);
        const int k = ks[i];
        if (k != curk) {                       // block-uniform branch (~2/segment)
            atomicAdd(&esum[(size_t)curk * DIM + d],     acc.x);
            atomicAdd(&esum[(size_t)curk * DIM + d + 1], acc.y);
            acc.x = 0.f; acc.y = 0.f;
            curk = k;
            er = *(const float2*)(E + (size_t)k * DIM + d);
        }
        *(float2*)(out0 + (size_t)t * DIM + d) = er;
        acc.x += v.x; acc.y += v.y;
        v = vn;
    }
    atomicAdd(&esum[(size_t)curk * DIM + d],     acc.x);
    atomicAdd(&esum[(size_t)curk * DIM + d + 1], acc.y);
}

__global__ __launch_bounds__(1024) void cs_n_kernel(const float* __restrict__ cs,
    const int* __restrict__ counts, float* __restrict__ out3,
    float* __restrict__ n_ws)
{
    const int k = threadIdx.x;
    const float ncs = 0.99f * cs[k] + 0.01f * (float)counts[k];
    out3[k] = ncs;
    float s = ncs;
    for (int off = 32; off > 0; off >>= 1) s += __shfl_down(s, off, 64);
    __shared__ float red[16];
    const int lane = k & 63, wv = k >> 6;
    if (lane == 0) red[wv] = s;
    __syncthreads();
    if (k == 0) {
        float t = 0.f;
        for (int i = 0; i < 16; ++i) t += red[i];
        n_ws[0] = t;
    }
}

__global__ __launch_bounds__(256) void out24_kernel(const float* __restrict__ ea,
    const float* __restrict__ esum, const float* __restrict__ out3,
    const float* __restrict__ n_ws, float* __restrict__ out2,
    float* __restrict__ out4)
{
    const size_t i = (size_t)blockIdx.x * 256 + threadIdx.x;
    const int k = (int)(i >> 9);
    const float n = n_ws[0];
    const float smoothed = (out3[k] + 1e-5f) / (n + 0.01024f) * n;
    const float nea = 0.99f * ea[i] + 0.01f * esum[i];
    out4[i] = nea;
    out2[i] = nea / smoothed;
}

extern "C" void kernel_launch(void* const* d_in, const int* in_sizes, int n_in,
                              void* d_out, int out_size, void* d_ws, size_t ws_size,
                              hipStream_t stream)
{
    const float* z  = (const float*)d_in[0];
    const float* E  = (const float*)d_in[1];
    const float* cs = (const float*)d_in[2];
    const float* ea = (const float*)d_in[3];

    float* out0 = (float*)d_out;                       // quantized_st [NTOK*DIM]
    float* out1 = out0 + (size_t)NTOK * DIM;           // indices (as f32) [NTOK]
    float* out2 = out1 + NTOK;                         // new_embedding [KCB*DIM]
    float* out3 = out2 + (size_t)KCB * DIM;            // new_cluster_size [KCB]
    float* out4 = out3 + KCB;                          // new_embed_avg [KCB*DIM]

    char* ws = (char*)d_ws;
    int*   idx_ws  = (int*)ws;
    float* esq     = (float*)(ws + 262144);
    int*   refCnt  = (int*)(ws + 266240);
    int*   refList = (int*)(ws + 266256);
    float* n_ws    = (float*)(ws + 282640);
    int*   counts  = (int*)(ws + 282656);
    int*   cursor  = (int*)(ws + 286752);
    int*   base    = (int*)(ws + 290848);
    u16*   Ehf     = (u16*)(ws + 294976);
    float* esum    = (float*)(ws + 294976);            // aliases Ehf (2 MB span)
    int*   toklist = (int*)out2;                       // out2 region as scratch

    hipMemsetAsync(refCnt, 0, sizeof(int), stream);
    hipMemsetAsync(counts, 0, KCB * sizeof(int), stream);

    esq_kernel<<<KCB / 4, 256, 0, stream>>>(E, esq);
    ehalf_kernel<<<(KCB * DIM / 2) / 256, 256, 0, stream>>>(E, Ehf);
    score_kernel<<<NTOK / 64, 256, 0, stream>>>(z, Ehf, esq, idx_ws, out1, refCnt, refList);
    // Ehf dead from here; zero esum over that region (stream-ordered)
    hipMemsetAsync(esum, 0, (size_t)KCB * DIM * sizeof(float), stream);
    refine_kernel<<<1024, 256, 0, stream>>>(z, E, refCnt, refList, idx_ws, out1);
    hist_kernel<<<NTOK / 1024, 256, 0, stream>>>(idx_ws, counts);
    scan_kernel<<<1, 1024, 0, stream>>>(counts, cursor, base);
    scatter_kernel<<<NTOK / 1024, 256, 0, stream>>>(idx_ws, cursor, toklist);
    seg_sum_kernel<<<NTOK / 64, 256, 0, stream>>>(z, E, toklist, idx_ws, out0, esum);
    cs_n_kernel<<<1, 1024, 0, stream>>>(cs, counts, out3, n_ws);
    out24_kernel<<<(KCB * DIM) / 256, 256, 0, stream>>>(ea, esum, out3, n_ws, out2, out4);
}